// Round 17
// baseline (83.028 us; speedup 1.0000x reference)
//
#include <hip/hip_runtime.h>

typedef __attribute__((ext_vector_type(8))) __bf16  bf16x8;
typedef __attribute__((ext_vector_type(8))) short   short8;
typedef __attribute__((ext_vector_type(4))) float   f32x4;

#define DM   512
#define BM   128
#define BN   128
#define BK   32
#define NNT  4                 // 128-col tiles (512/128)
#define NKT  16                // k-tiles (512/32)
#define TILEB (BN*BK*2)        // 8 KiB per B tile image

__device__ __forceinline__ short f2bf(float f) {
  union { float f; unsigned u; } v; v.f = f;
  unsigned r = v.u + 0x7fffu + ((v.u >> 16) & 1u);   // RNE
  return (short)(r >> 16);
}

// XOR swizzle within a [rows][32 bf16] tile (64B row stride), 16B granular.
__device__ __forceinline__ int swz(int r, int cbyte) {
  return (r * 64 + cbyte) ^ ((r & 3) << 4);
}

// Fold softmax(taps) + conv into per-head G[h][e][d], stored as pre-swizzled
// per-(h,nt,kt) 128x32 LDS tile images. 8 d's per thread.
__global__ void build_g_kernel(const float* __restrict__ w,
                               const float* __restrict__ fcw,
                               short* __restrict__ Gt) {
  int idx = blockIdx.x * 256 + threadIdx.x;   // 8*512*512/8 threads
  int h  = idx >> 15;
  int t  = idx & 32767;
  int e  = t >> 6;
  int d0 = (t & 63) << 3;
  float w0 = w[h*3+0], w1 = w[h*3+1], w2 = w[h*3+2];
  float mx = fmaxf(w0, fmaxf(w1, w2));
  float e0 = __expf(w0-mx), e1 = __expf(w1-mx), e2 = __expf(w2-mx);
  float inv = 1.0f / (e0 + e1 + e2);
  float w0n = e0*inv, w1n = e1*inv, w2n = e2*inv;
  const float* row = fcw + e * DM;
  float v[10];
  v[0] = (d0 > 0) ? row[d0-1] : 0.0f;
  float4 a = *(const float4*)(row + d0);
  float4 b = *(const float4*)(row + d0 + 4);
  v[1]=a.x; v[2]=a.y; v[3]=a.z; v[4]=a.w;
  v[5]=b.x; v[6]=b.y; v[7]=b.z; v[8]=b.w;
  v[9] = (d0 + 8 < DM) ? row[d0+8] : 0.0f;
  short8 sv;
  #pragma unroll
  for (int j = 0; j < 8; ++j)
    sv[j] = f2bf(w1n*v[j+1] + w0n*v[j+2] + w2n*v[j]);
  int nt = e >> 7, r = e & 127;
  int kt = d0 >> 5, c = d0 & 31;
  char* tile = (char*)Gt + (size_t)((h * NNT + nt) * NKT + kt) * TILEB;
  *(short8*)(tile + swz(r, c * 2)) = sv;
}

// y[R,e] = sum_d x[R,d] * G[R%8][e,d]; R = h + 8*t
// 2-nt blocks: one staged A tile feeds TWO 128-col B tiles (32 MFMA/barrier,
// A traffic + convert VALU halved).  2 blocks/CU (48 KiB LDS, ~220 VGPR).
__global__ __launch_bounds__(256, 2) void gemm_kernel(const float* __restrict__ x,
                                                      const short* __restrict__ Gt,
                                                      float* __restrict__ out) {
  int bid = blockIdx.x;          // 1024 blocks
  int h   = bid & 7;             // head == XCD
  int idx = bid >> 3;
  int nt2 = idx & 1;             // which 256-col half; pairs share A via L2
  int mt  = idx >> 1;            // 64 mtiles
  int tid  = threadIdx.x;
  int lane = tid & 63;
  int wid  = tid >> 6;
  int wr = wid >> 1, wc = wid & 1;   // 2x2 wave grid; wave tile 64 x 128
  int ln = lane & 15, sf = lane >> 4;

  __shared__ char Alds[2][TILEB];       // 2 x 8 KiB swizzled
  __shared__ char Blds[2][2 * TILEB];   // 2 buf x 2 tiles x 8 KiB

  const char* Bsrc0 = (const char*)Gt + (size_t)((h * NNT + nt2 * 2) * NKT) * TILEB;
  const float* Abase = x + (size_t)(h + 8 * (size_t)mt * BM) * DM;

  float4 ap[4];   // A prefetch regs (16 VGPR)

  auto loadA = [&](int kt) {
    #pragma unroll
    for (int p = 0; p < 2; ++p) {
      int r = (tid >> 2) + 64 * p;
      const float* xr = Abase + (size_t)r * 8 * DM + kt * BK + (tid & 3) * 8;
      ap[2*p]   = *(const float4*)xr;
      ap[2*p+1] = *(const float4*)(xr + 4);
    }
  };
  auto stageB = [&](int kt, int buf) {   // 2 tiles x 2 gload_lds per thread
    char* dst = Blds[buf];
    #pragma unroll
    for (int t = 0; t < 2; ++t) {
      const char* src = Bsrc0 + ((size_t)t * NKT + kt) * TILEB;
      #pragma unroll
      for (int p = 0; p < 2; ++p)
        __builtin_amdgcn_global_load_lds((const void*)(src + p * 4096 + tid * 16),
                                         (void*)(dst + t * TILEB + p * 4096 + wid * 1024),
                                         16, 0, 0);
    }
  };
  auto writeA = [&](int buf) {
    char* dst = Alds[buf];
    #pragma unroll
    for (int p = 0; p < 2; ++p) {
      int r = (tid >> 2) + 64 * p;
      short8 sv;
      sv[0]=f2bf(ap[2*p].x);   sv[1]=f2bf(ap[2*p].y);
      sv[2]=f2bf(ap[2*p].z);   sv[3]=f2bf(ap[2*p].w);
      sv[4]=f2bf(ap[2*p+1].x); sv[5]=f2bf(ap[2*p+1].y);
      sv[6]=f2bf(ap[2*p+1].z); sv[7]=f2bf(ap[2*p+1].w);
      *(short8*)(dst + swz(r, (tid & 3) * 16)) = sv;
    }
  };

  f32x4 acc[4][8] = {};   // wave tile 64 x 128 (128 VGPR)

  auto computeTile = [&](int cur) {
    const char* Ap = Alds[cur];
    const char* Bp = Blds[cur];
    bf16x8 af[4], bfr[8];
    #pragma unroll
    for (int m = 0; m < 4; ++m)
      af[m] = *(const bf16x8*)(Ap + swz(wr*64 + m*16 + ln, sf * 16));
    #pragma unroll
    for (int n = 0; n < 8; ++n)
      bfr[n] = *(const bf16x8*)(Bp + (n >> 2) * TILEB
                                   + swz(wc*64 + (n & 3)*16 + ln, sf * 16));
    #pragma unroll
    for (int m = 0; m < 4; ++m)
      #pragma unroll
      for (int n = 0; n < 8; ++n)
        acc[m][n] = __builtin_amdgcn_mfma_f32_16x16x32_bf16(af[m], bfr[n], acc[m][n], 0, 0, 0);
  };

  // prologue: tile 0 -> buf 0
  loadA(0);
  stageB(0, 0);
  writeA(0);
  __syncthreads();

  for (int kt = 0; kt < NKT; ++kt) {
    int cur = kt & 1, nxt = cur ^ 1;
    if (kt + 1 < NKT) {            // issue next tile's loads before compute
      loadA(kt + 1);
      stageB(kt + 1, nxt);
    }
    computeTile(cur);
    if (kt + 1 < NKT) writeA(nxt); // convert + ds_write after compute
    __syncthreads();               // boundary drain
  }

  // epilogue: C/D layout col = lane&15, row = (lane>>4)*4 + j
  #pragma unroll
  for (int m = 0; m < 4; ++m) {
    int tq = mt * BM + wr * 64 + m * 16 + (sf << 2);
    #pragma unroll
    for (int j = 0; j < 4; ++j) {
      int R = h + 8 * (tq + j);
      float* orow = out + (size_t)R * DM;
      #pragma unroll
      for (int n = 0; n < 8; ++n) {
        int e0 = nt2 * 256 + (n >> 2) * 128 + wc * 64 + (n & 3) * 16 + ln;
        orow[e0] = acc[m][n][j];
      }
    }
  }
}

extern "C" void kernel_launch(void* const* d_in, const int* in_sizes, int n_in,
                              void* d_out, int out_size, void* d_ws, size_t ws_size,
                              hipStream_t stream) {
  const float* x   = (const float*)d_in[0];
  const float* w   = (const float*)d_in[1];
  const float* fcw = (const float*)d_in[2];
  float* out = (float*)d_out;
  short* Gt  = (short*)d_ws;   // 8*4*16 tiles * 8 KiB = 4 MiB pre-swizzled

  hipLaunchKernelGGL(build_g_kernel, dim3((8 * DM * DM / 8) / 256), dim3(256), 0, stream,
                     w, fcw, Gt);
  hipLaunchKernelGGL(gemm_kernel, dim3(8 * 64 * 2), dim3(256), 0, stream,
                     x, Gt, out);
}